// Round 1
// baseline (262.086 us; speedup 1.0000x reference)
//
#include <hip/hip_runtime.h>

#define NBLOCKS 1024
#define NTHREADS 256
// Per-tile: NTHREADS threads x 4 float4 = 1024 float4 = 16 KB per array.
#define TILE_V4 (NTHREADS * 4)

typedef float vf4 __attribute__((ext_vector_type(4)));

// Async global->LDS DMA (gfx950, width=16). LDS dest is wave-uniform base +
// lane*16; our layout is contiguous in threadIdx order, which satisfies it.
__device__ __forceinline__ void stage16(const vf4* g, vf4* l) {
    __builtin_amdgcn_global_load_lds(
        (const __attribute__((address_space(1))) void*)g,
        (__attribute__((address_space(3))) void*)l,
        16, 0, 0);
}

__global__ __launch_bounds__(NTHREADS) void loss1_partial(
    const float* __restrict__ x, const float* __restrict__ y,
    long long n, float* __restrict__ psum, int* __restrict__ pcnt) {
    const long long nvec = n >> 2;
    const long long ntiles = nvec / TILE_V4;
    const vf4* __restrict__ x4 = (const vf4*)x;
    const vf4* __restrict__ y4 = (const vf4*)y;

    // Double-buffered y tile: 2 x 16 KB = 32 KB -> 5 blocks/CU by LDS,
    // grid gives 4 blocks/CU (16 waves/CU) fully resident & persistent.
    __shared__ vf4 ybuf[2][TILE_V4];

    float s  = 0.0f;
    int   cw = 0;   // wave-uniform count (ballot/popcount, SALU pipe)
    int   ct = 0;   // per-lane count (tail path only)

    long long t = blockIdx.x;
    bool have = (t < ntiles);
    vf4 a0, a1, a2, a3;

    // Prologue: issue tile t0's 8 vmem ops (4 DMA -> ybuf[0], 4 x -> VGPR).
    if (have) {
        long long p = t * TILE_V4 + threadIdx.x;
        #pragma unroll
        for (int u = 0; u < 4; ++u)
            stage16(&y4[p + u * NTHREADS], &ybuf[0][threadIdx.x + u * NTHREADS]);
        a0 = __builtin_nontemporal_load(&x4[p]);
        a1 = __builtin_nontemporal_load(&x4[p + NTHREADS]);
        a2 = __builtin_nontemporal_load(&x4[p + 2 * NTHREADS]);
        a3 = __builtin_nontemporal_load(&x4[p + 3 * NTHREADS]);
    }

    int cur = 0;
    while (have) {
        const long long tn = t + gridDim.x;     // block-uniform
        const bool haven = (tn < ntiles);       // block-uniform branch

        // Issue NEXT tile's 8 loads before computing the current one.
        vf4 na0, na1, na2, na3;
        if (haven) {
            long long pn = tn * TILE_V4 + threadIdx.x;
            #pragma unroll
            for (int u = 0; u < 4; ++u)
                stage16(&y4[pn + u * NTHREADS],
                        &ybuf[cur ^ 1][threadIdx.x + u * NTHREADS]);
            na0 = __builtin_nontemporal_load(&x4[pn]);
            na1 = __builtin_nontemporal_load(&x4[pn + NTHREADS]);
            na2 = __builtin_nontemporal_load(&x4[pn + 2 * NTHREADS]);
            na3 = __builtin_nontemporal_load(&x4[pn + 3 * NTHREADS]);
        }

        // Counted wait: retire the CURRENT tile's 8 loads, leave the 8
        // prefetch loads in flight across the barrier (T4 discipline —
        // never vmcnt(0) in the steady-state loop).
        if (haven) {
            asm volatile("s_waitcnt vmcnt(8)" ::: "memory");
        } else {
            asm volatile("s_waitcnt vmcnt(0)" ::: "memory");
        }
        __builtin_amdgcn_sched_barrier(0);
        __builtin_amdgcn_s_barrier();          // ybuf[cur] staged for ALL waves
        __builtin_amdgcn_sched_barrier(0);

        vf4 b0 = ybuf[cur][threadIdx.x];
        vf4 b1 = ybuf[cur][threadIdx.x + NTHREADS];
        vf4 b2 = ybuf[cur][threadIdx.x + 2 * NTHREADS];
        vf4 b3 = ybuf[cur][threadIdx.x + 3 * NTHREADS];

        // s += max(x-y, 0) ; count via ballot -> s_bcnt1 on the scalar pipe
        // (wave-uniform cw; every lane holds the same value).
        #pragma unroll
        for (int k = 0; k < 4; ++k) {
            float d0 = a0[k] - b0[k];
            float d1 = a1[k] - b1[k];
            float d2 = a2[k] - b2[k];
            float d3 = a3[k] - b3[k];
            s += fmaxf(d0, 0.0f);
            s += fmaxf(d1, 0.0f);
            s += fmaxf(d2, 0.0f);
            s += fmaxf(d3, 0.0f);
            cw += (int)__popcll(__ballot(a0[k] > b0[k]));
            cw += (int)__popcll(__ballot(a1[k] > b1[k]));
            cw += (int)__popcll(__ballot(a2[k] > b2[k]));
            cw += (int)__popcll(__ballot(a3[k] > b3[k]));
        }

        // All ds_reads must have retired before other waves' next-tile DMA
        // may overwrite ybuf[cur] (DMA of iter t+1 targets buffer `cur`).
        asm volatile("s_waitcnt lgkmcnt(0)" ::: "memory");
        __builtin_amdgcn_sched_barrier(0);
        __builtin_amdgcn_s_barrier();          // all waves done reading ybuf[cur]
        __builtin_amdgcn_sched_barrier(0);

        if (haven) { a0 = na0; a1 = na1; a2 = na2; a3 = na3; }
        cur ^= 1;
        t = tn;
        have = haven;
    }

    // float4 tail beyond the last full tile (none for this shape)
    {
        long long gtid = (long long)blockIdx.x * blockDim.x + threadIdx.x;
        long long gstride = (long long)gridDim.x * blockDim.x;
        for (long long i = ntiles * TILE_V4 + gtid; i < nvec; i += gstride) {
            vf4 a = x4[i];
            vf4 b = y4[i];
            #pragma unroll
            for (int k = 0; k < 4; ++k) {
                s += (a[k] > b[k]) ? (a[k] - b[k]) : 0.0f;  ct += (a[k] > b[k]);
            }
        }
        if (gtid == 0) {
            for (long long j = nvec << 2; j < n; ++j) {
                float d = x[j] - y[j];
                if (x[j] > y[j]) { s += d; ct += 1; }
            }
        }
    }

    // wave-64 shuffle reduction (s and per-lane tail count only;
    // cw is already wave-uniform)
    #pragma unroll
    for (int off = 32; off > 0; off >>= 1) {
        s  += __shfl_down(s, off, 64);
        ct += __shfl_down(ct, off, 64);
    }

    __shared__ float ss[NTHREADS / 64];
    __shared__ int   sc[NTHREADS / 64];
    int lane = threadIdx.x & 63;
    int wave = threadIdx.x >> 6;
    if (lane == 0) { ss[wave] = s; sc[wave] = ct + cw; }
    __syncthreads();
    if (threadIdx.x == 0) {
        float ts = 0.0f; int tc = 0;
        #pragma unroll
        for (int w = 0; w < NTHREADS / 64; ++w) { ts += ss[w]; tc += sc[w]; }
        psum[blockIdx.x] = ts;
        pcnt[blockIdx.x] = tc;
    }
}

__global__ __launch_bounds__(1024) void loss1_final(
    const float* __restrict__ psum, const int* __restrict__ pcnt,
    int nparts, float* __restrict__ out) {
    int tid = threadIdx.x;
    float s = 0.0f;
    int c = 0;
    for (int i = tid; i < nparts; i += 1024) {
        s += psum[i];
        c += pcnt[i];
    }
    #pragma unroll
    for (int off = 32; off > 0; off >>= 1) {
        s += __shfl_down(s, off, 64);
        c += __shfl_down(c, off, 64);
    }
    __shared__ float ss[16];
    __shared__ int   sc[16];
    int lane = tid & 63;
    int wave = tid >> 6;
    if (lane == 0) { ss[wave] = s; sc[wave] = c; }
    __syncthreads();
    if (tid == 0) {
        float ts = 0.0f; int tc = 0;
        #pragma unroll
        for (int w = 0; w < 16; ++w) { ts += ss[w]; tc += sc[w]; }
        out[0] = (tc > 0) ? (ts / (float)tc) : 0.0f;
    }
}

extern "C" void kernel_launch(void* const* d_in, const int* in_sizes, int n_in,
                              void* d_out, int out_size, void* d_ws, size_t ws_size,
                              hipStream_t stream) {
    const float* x = (const float*)d_in[0];
    const float* y = (const float*)d_in[1];
    long long n = (long long)in_sizes[0];

    float* psum = (float*)d_ws;
    int*   pcnt = (int*)((char*)d_ws + NBLOCKS * sizeof(float));

    loss1_partial<<<NBLOCKS, NTHREADS, 0, stream>>>(x, y, n, psum, pcnt);
    loss1_final<<<1, 1024, 0, stream>>>(psum, pcnt, NBLOCKS, (float*)d_out);
}